// Round 9
// baseline (156961.267 us; speedup 1.0000x reference)
//
#include <hip/hip_runtime.h>
#include <hip/hip_bf16.h>
#include <stdint.h>

// AutoRegressive LSTM (B=1024, T=256, I=64, U=1024, S=64) on MI355X.
// R9: persistent per-XCD kernel with NO per-step global barrier. Per-rank
// completion flags (1 release store/CU/step); consumers poll only the 2
// producer ranks of each A-chunk, 2 chunks ahead. x-chunk processed LAST
// (order 1..16,0) so distributed in-kernel x-prep has a full step of slack.
// B weights: 4 chunks reg-pinned + 3 LDS-pinned + rest streamed (3-buf,
// exact constexpr vmcnt ledger). 512 thr / 8 waves (2/SIMD TLP).

typedef _Float16 f16;
typedef _Float16 f16x8 __attribute__((ext_vector_type(8)));
typedef _Float16 f16x4 __attribute__((ext_vector_type(4)));
typedef float f32x4 __attribute__((ext_vector_type(4)));

#define CHH 8192  // halves per [128 cols][64 k] weight tile (16KB)

template <bool WARM> struct Sch {
  static constexpr int NPOS = WARM ? 17 : 16;
  static constexpr int ord(int p) { return WARM ? (p < 16 ? p + 1 : 0) : p; }
  static constexpr bool streamed(int c) { return WARM ? (c == 0 || c >= 8) : (c >= 7); }
  static constexpr int regpin(int c) { return WARM ? ((c >= 1 && c <= 4) ? c - 1 : -1)
                                                   : ((c <= 3) ? c : -1); }
  static constexpr int ldspin(int c) { return WARM ? ((c >= 5 && c <= 7) ? c - 5 : -1)
                                                   : ((c >= 4 && c <= 6) ? c - 4 : -1); }
  static constexpr int waitN(int p) {
    return (p + 1 < NPOS) ? (2 + (streamed(ord(p + 1)) ? 2 : 0)) : 0;
  }
};

__device__ __forceinline__ void gl_lds_a(const char* src_lane, const f16* dst_wave) {
  __builtin_amdgcn_global_load_lds(
      (const __attribute__((address_space(1))) unsigned int*)src_lane,
      (__attribute__((address_space(3))) unsigned int*)dst_wave, 16, 0, 1);  // sc0
}
__device__ __forceinline__ void gl_lds_w(const char* src_lane, const f16* dst_wave) {
  __builtin_amdgcn_global_load_lds(
      (const __attribute__((address_space(1))) unsigned int*)src_lane,
      (__attribute__((address_space(3))) unsigned int*)dst_wave, 16, 0, 0);
}

__device__ __forceinline__ float sigf(float x) { return 1.0f / (1.0f + __expf(-x)); }
__device__ __forceinline__ float tanhfast(float x) { return 1.0f - 2.0f / (__expf(2.0f * x) + 1.0f); }

struct Env {
  const char* hA;      // h input, natural [row][1024] fp16 (bytes)
  const char* xb;      // x tile, natural [row][64] fp16 (bytes)
  const char* panel;   // weight panel base (bytes, swizzled tiles)
  f16 (*Abuf)[CHH];
  f16 (*Bbuf)[CHH];
  f16* WpL;
  unsigned* flags;     // per-rank step counters, stride 16 u32
  int fbase;           // xcd*32
  unsigned tgt;        // current step t (producers must be >= t)
  int w, lane, rw, cw, ln15, ln4;
  size_t hoff0, hoff1, xoff0, xoff1;
};

__device__ __forceinline__ void waitPair(unsigned* flags, int base, int r0, unsigned tgt) {
  int guard = 0;
  while (__hip_atomic_load(&flags[(base + r0) * 16], __ATOMIC_ACQUIRE, __HIP_MEMORY_SCOPE_AGENT) < tgt ||
         __hip_atomic_load(&flags[(base + r0 + 1) * 16], __ATOMIC_ACQUIRE, __HIP_MEMORY_SCOPE_AGENT) < tgt) {
    __builtin_amdgcn_s_sleep(1);
    if (++guard > (1 << 24)) break;
  }
}

template <bool WARM, int Q>
__device__ __forceinline__ void issuePos(Env& e) {
  constexpr int C2 = Sch<WARM>::ord(Q);
  // producer-pair flag check (x chunk: covered by prior pair checks)
  if constexpr (!(WARM && C2 == 0)) waitPair(e.flags, e.fbase, WARM ? 2 * (C2 - 1) : 2 * C2, e.tgt);
  f16* slot = e.Abuf[Q % 3];
  if constexpr (WARM && C2 == 0) {
    gl_lds_a(e.xb + e.xoff0, slot + e.w * 512);
    gl_lds_a(e.xb + e.xoff1, slot + 4096 + e.w * 512);
  } else {
    const char* base = e.hA + (size_t)(WARM ? C2 - 1 : C2) * 128;
    gl_lds_a(base + e.hoff0, slot + e.w * 512);
    gl_lds_a(base + e.hoff1, slot + 4096 + e.w * 512);
  }
  if constexpr (Sch<WARM>::streamed(C2)) {
    f16* bs = e.Bbuf[Q % 3];
    const char* src = e.panel + (size_t)C2 * 16384 + (size_t)e.w * 1024 + (size_t)e.lane * 16;
    gl_lds_w(src, bs + e.w * 512);
    gl_lds_w(src + 8192, bs + 4096 + e.w * 512);
  }
}

template <bool WARM, int P>
__device__ __forceinline__ void computePos(Env& e, const f16x8 (&bpin)[4][2][4], f32x4 (&acc)[2][4]) {
  constexpr int C = Sch<WARM>::ord(P);
  const f16* Ab = e.Abuf[P % 3];
#pragma unroll
  for (int kc = 0; kc < 2; kc++) {
    const int gx = ((4 * kc + e.ln4) ^ (e.ln15 & 7)) * 8;
    f16x8 af[2], bf[4];
#pragma unroll
    for (int mf = 0; mf < 2; mf++)
      af[mf] = *(const f16x8*)(Ab + (32 * e.rw + 16 * mf + e.ln15) * 64 + gx);
    if constexpr (Sch<WARM>::regpin(C) >= 0) {
#pragma unroll
      for (int nf = 0; nf < 4; nf++) bf[nf] = bpin[Sch<WARM>::regpin(C)][kc][nf];
    } else if constexpr (Sch<WARM>::ldspin(C) >= 0) {
      const f16* Bb = e.WpL + Sch<WARM>::ldspin(C) * CHH;
#pragma unroll
      for (int nf = 0; nf < 4; nf++)
        bf[nf] = *(const f16x8*)(Bb + (64 * e.cw + 16 * nf + e.ln15) * 64 + gx);
    } else {
      const f16* Bb = e.Bbuf[P % 3];
#pragma unroll
      for (int nf = 0; nf < 4; nf++)
        bf[nf] = *(const f16x8*)(Bb + (64 * e.cw + 16 * nf + e.ln15) * 64 + gx);
    }
    __builtin_amdgcn_s_setprio(1);
#pragma unroll
    for (int mf = 0; mf < 2; mf++)
#pragma unroll
      for (int nf = 0; nf < 4; nf++)
        acc[mf][nf] = __builtin_amdgcn_mfma_f32_16x16x32_f16(af[mf], bf[nf], acc[mf][nf], 0, 0, 0);
    __builtin_amdgcn_s_setprio(0);
  }
}

template <bool WARM>
__device__ __forceinline__ void runStep(Env& e, const f16x8 (&bpin)[4][2][4], f32x4 (&acc)[2][4]) {
  issuePos<WARM, 0>(e);
  issuePos<WARM, 1>(e);
#define IT_(P)                                                                  \
  if constexpr (P < Sch<WARM>::NPOS) {                                          \
    asm volatile("s_waitcnt vmcnt(%0)" ::"n"(Sch<WARM>::waitN(P)));             \
    __builtin_amdgcn_s_barrier();                                               \
    __builtin_amdgcn_sched_barrier(0);                                          \
    if constexpr (P + 2 < Sch<WARM>::NPOS) issuePos<WARM, P + 2>(e);            \
    computePos<WARM, P>(e, bpin, acc);                                          \
  }
  IT_(0) IT_(1) IT_(2) IT_(3) IT_(4) IT_(5) IT_(6) IT_(7) IT_(8)
  IT_(9) IT_(10) IT_(11) IT_(12) IT_(13) IT_(14) IT_(15) IT_(16)
#undef IT_
}

// ---------------- persistent LSTM kernel ----------------
__global__ void __launch_bounds__(512, 1) lstm_persist(
    const f16* __restrict__ WT, const f16* __restrict__ WPT,
    const float* __restrict__ inputs,
    f16* __restrict__ hbA, f16* __restrict__ xbuf,
    float* __restrict__ ppart,
    const float* __restrict__ bperm, const float* __restrict__ bperm2,
    const float* __restrict__ Wd, const float* __restrict__ bd,
    const int* __restrict__ oidx, float* __restrict__ out,
    int n_idx, unsigned* __restrict__ sync) {
  const int tid = threadIdx.x;

  __shared__ __align__(16) f16 WpL[3 * CHH];     // 48KB pinned B
  __shared__ __align__(16) f16 Abuf[3][CHH];     // 48KB
  __shared__ __align__(16) f16 Bbuf[3][CHH];     // 48KB  (144KB)

  unsigned xcd;
  asm("s_getreg_b32 %0, hwreg(HW_REG_XCC_ID)" : "=s"(xcd));
  xcd &= 7u;
  unsigned* flags = sync;                 // [xcd*32+rank]*16
  unsigned* rank_ctr = sync + 4096;       // [xcd*16]
  if (tid == 0) {
    unsigned r = __hip_atomic_fetch_add(&rank_ctr[xcd * 16], 1u, __ATOMIC_RELAXED,
                                        __HIP_MEMORY_SCOPE_AGENT) & 31u;
    *(volatile unsigned short*)WpL = (unsigned short)r;
  }
  __syncthreads();
  const int ni = (int)*(volatile unsigned short*)WpL;
  __syncthreads();
  const int mi = (int)xcd;
  const int fbase = mi * 32;

  const int w = tid >> 6, lane = tid & 63;
  const int rw = w >> 1, cw = w & 1, ln15 = lane & 15, ln4 = lane >> 4;
  const int u_glob = 32 * ni + 16 * cw + ln15;

  // staging lane constants
  const int l3 = lane >> 3, g8 = lane & 7;
  const int gsw = g8 ^ (l3 & 7);
  const int row_s = w * 8 + l3;

  Env e;
  e.Abuf = Abuf; e.Bbuf = Bbuf; e.WpL = WpL;
  e.flags = flags; e.fbase = fbase;
  e.w = w; e.lane = lane; e.rw = rw; e.cw = cw; e.ln15 = ln15; e.ln4 = ln4;
  e.hoff0 = (size_t)row_s * 2048 + (size_t)gsw * 16;
  e.hoff1 = (size_t)(row_s + 64) * 2048 + (size_t)gsw * 16;
  e.xoff0 = (size_t)row_s * 128 + (size_t)gsw * 16;
  e.xoff1 = (size_t)(row_s + 64) * 128 + (size_t)gsw * 16;

  // biases + Wd cols
  float biw[4], bi2[4];
#pragma unroll
  for (int nf = 0; nf < 4; nf++) {
    biw[nf] = bperm[ni * 128 + 64 * cw + 16 * nf + ln15];
    bi2[nf] = bperm2[ni * 128 + 64 * cw + 16 * nf + ln15];
  }
  float wdj[8];
#pragma unroll
  for (int j = 0; j < 8; j++) wdj[j] = 0.f;
  for (int j = 0; j < n_idx; j++) wdj[j] = Wd[(size_t)u_glob * 64 + oidx[j]];

  float cst[2][4];
#pragma unroll
  for (int a = 0; a < 2; a++)
#pragma unroll
    for (int q = 0; q < 4; q++) cst[a][q] = 0.f;

  const char* Wsw = (const char*)(WT + (size_t)ni * 17 * CHH);
  const char* Wsd = (const char*)(WPT + (size_t)ni * 16 * CHH);

  // init: reg-pin warm chunks 1..4; LDS-pin warm chunks 5..7
  f16x8 bpin[4][2][4];
  {
    const f16* p = (const f16*)Wsw;
#pragma unroll
    for (int cp = 0; cp < 4; cp++)
#pragma unroll
      for (int kc = 0; kc < 2; kc++) {
        const int gx = ((4 * kc + ln4) ^ (ln15 & 7)) * 8;
#pragma unroll
        for (int nf = 0; nf < 4; nf++)
          bpin[cp][kc][nf] = *(const f16x8*)(p + (size_t)(1 + cp) * CHH +
                                             (64 * cw + 16 * nf + ln15) * 64 + gx);
      }
#pragma unroll
    for (int i = 0; i < 6; i++)
      gl_lds_w(Wsw + 5 * 16384 + (size_t)(i * 8 + w) * 1024 + (size_t)lane * 16,
               WpL + (i * 8 + w) * 512);
    asm volatile("s_waitcnt vmcnt(0)" ::: "memory");
  }
  __syncthreads();

  for (int t = 0; t < 319; ++t) {
    const bool warm = (t < 256);
    if (t == 256) {
      // swap pins to W'
      const f16* p = (const f16*)Wsd;
#pragma unroll
      for (int cp = 0; cp < 4; cp++)
#pragma unroll
        for (int kc = 0; kc < 2; kc++) {
          const int gx = ((4 * kc + ln4) ^ (ln15 & 7)) * 8;
#pragma unroll
          for (int nf = 0; nf < 4; nf++)
            bpin[cp][kc][nf] = *(const f16x8*)(p + (size_t)cp * CHH +
                                               (64 * cw + 16 * nf + ln15) * 64 + gx);
        }
#pragma unroll
      for (int i = 0; i < 6; i++)
        gl_lds_w(Wsd + 4 * 16384 + (size_t)(i * 8 + w) * 1024 + (size_t)lane * 16,
                 WpL + (i * 8 + w) * 512);
      asm volatile("s_waitcnt vmcnt(0)" ::: "memory");
      __syncthreads();
    }

    e.hA = (const char*)(hbA + (size_t)((t & 1) * 8 + mi) * 131072);
    f16* hW = hbA + (size_t)(((t + 1) & 1) * 8 + mi) * 131072;
    e.xb = (const char*)(xbuf + (size_t)((t & 1) * 8 + mi) * CHH);
    e.panel = warm ? Wsw : Wsd;
    e.tgt = (unsigned)t;

    f32x4 acc[2][4];
#pragma unroll
    for (int a = 0; a < 2; a++)
#pragma unroll
      for (int q = 0; q < 4; q++) acc[a][q] = (f32x4){0.f, 0.f, 0.f, 0.f};

    if (warm) runStep<true>(e, bpin, acc);
    else      runStep<false>(e, bpin, acc);

    // ---- epilogue: gates -> c (regs), h (natural [row][1024]) ----
    const float b0 = warm ? biw[0] : bi2[0];
    const float b1 = warm ? biw[1] : bi2[1];
    const float b2v = warm ? biw[2] : bi2[2];
    const float b3 = warm ? biw[3] : bi2[3];
    float hv[2][4];
#pragma unroll
    for (int mf = 0; mf < 2; mf++) {
#pragma unroll
      for (int reg = 0; reg < 4; reg++) {
        const int r = 32 * rw + 16 * mf + 4 * ln4 + reg;
        const float zi = acc[mf][0][reg] + b0;
        const float zf = acc[mf][1][reg] + b1;
        const float zg = acc[mf][2][reg] + b2v;
        const float zo = acc[mf][3][reg] + b3;
        const float cn = sigf(zf) * cst[mf][reg] + sigf(zi) * tanhfast(zg);
        const float hn = sigf(zo) * tanhfast(cn);
        cst[mf][reg] = cn;
        hv[mf][reg] = hn;
        hW[(size_t)r * 1024 + u_glob] = (f16)hn;
      }
    }

    // ---- decode output partials (h(t)·Wd cols) ----
    if (t >= 255) {
      const int sbw = t & 1;
      for (int j = 0; j < n_idx; j++) {
        const float wd = wdj[j];
#pragma unroll
        for (int mf = 0; mf < 2; mf++)
#pragma unroll
          for (int reg = 0; reg < 4; reg++) {
            float v = hv[mf][reg] * wd;
            v += __shfl_xor(v, 1);
            v += __shfl_xor(v, 2);
            v += __shfl_xor(v, 4);
            v += __shfl_xor(v, 8);
            if (ln15 == 0) {
              const int r = 32 * rw + 16 * mf + 4 * ln4 + reg;
              const size_t idx = ((((size_t)(sbw * 8 + mi) * 32 + ni) * 8 + j) * 2 + cw) * 128 + r;
              ppart[idx] = v;
            }
          }
      }
    }

    // ---- out reduce for s = t-256 (partials written at t-1, flags observed) ----
    if (t >= 256) {
      const int s = t - 256;
      const int sb = (t - 1) & 1;
      const int nwork = 4 * n_idx * 8;
      if (tid < nwork) {
        const int qg = tid & 7, rj = tid >> 3;
        const int j = rj % n_idx, r4 = rj / n_idx;
        const int row = 4 * ni + r4;
        float a2 = 0.f;
#pragma unroll
        for (int qq = 0; qq < 4; qq++) {
          const int q = 4 * qg + qq;
#pragma unroll
          for (int c2 = 0; c2 < 2; c2++) {
            const size_t idx = ((((size_t)(sb * 8 + mi) * 32 + q) * 8 + j) * 2 + c2) * 128 + row;
            a2 += __hip_atomic_load(&ppart[idx], __ATOMIC_RELAXED, __HIP_MEMORY_SCOPE_AGENT);
          }
        }
        a2 += __shfl_xor(a2, 1);
        a2 += __shfl_xor(a2, 2);
        a2 += __shfl_xor(a2, 4);
        if (qg == 0) out[((size_t)(128 * mi + row) * 64 + s) * n_idx + j] = a2 + bd[oidx[j]];
      }
    }

    // ---- distributed x-prep for step t+1 (4 rows per rank) ----
    if (warm && (t + 1 < 256) && tid >= 448) {
      const int l = tid - 448;
      const int row = 4 * ni + (l >> 4), cg = l & 15;
      const float4 a = *(const float4*)(inputs + (size_t)(128 * mi + row) * 16384 +
                                        (size_t)(t + 1) * 64 + cg * 4);
      f16x4 v;
      v[0] = (f16)a.x; v[1] = (f16)a.y; v[2] = (f16)a.z; v[3] = (f16)a.w;
      *(f16x4*)(xbuf + (size_t)(((t + 1) & 1) * 8 + mi) * CHH + (size_t)row * 64 + cg * 4) = v;
    }

    // ---- drain, publish completion flag ----
    asm volatile("s_waitcnt vmcnt(0)" ::: "memory");
    __builtin_amdgcn_s_barrier();
    if (tid == 0)
      __hip_atomic_store(&flags[(fbase + ni) * 16], (unsigned)(t + 1),
                         __ATOMIC_RELEASE, __HIP_MEMORY_SCOPE_AGENT);
  }

  // ---- final: wait all ranks done 319, reduce s=63 ----
  if (tid < 32) {
    int guard = 0;
    while (__hip_atomic_load(&flags[(fbase + tid) * 16], __ATOMIC_ACQUIRE,
                             __HIP_MEMORY_SCOPE_AGENT) < 319u) {
      __builtin_amdgcn_s_sleep(1);
      if (++guard > (1 << 24)) break;
    }
  }
  __builtin_amdgcn_s_barrier();
  {
    const int nwork = 4 * n_idx * 8;
    if (tid < nwork) {
      const int qg = tid & 7, rj = tid >> 3;
      const int j = rj % n_idx, r4 = rj / n_idx;
      const int row = 4 * ni + r4;
      float a2 = 0.f;
#pragma unroll
      for (int qq = 0; qq < 4; qq++) {
        const int q = 4 * qg + qq;
#pragma unroll
        for (int c2 = 0; c2 < 2; c2++) {
          const size_t idx = ((((size_t)mi * 32 + q) * 8 + j) * 2 + c2) * 128 + row;
          a2 += __hip_atomic_load(&ppart[idx], __ATOMIC_RELAXED, __HIP_MEMORY_SCOPE_AGENT);
        }
      }
      a2 += __shfl_xor(a2, 1);
      a2 += __shfl_xor(a2, 2);
      a2 += __shfl_xor(a2, 4);
      if (qg == 0) out[((size_t)(128 * mi + row) * 64 + 63) * n_idx + j] = a2 + bd[oidx[j]];
    }
  }
}

// ---------------- prep kernels (R8 layouts, unchanged) ----------------
__global__ void __launch_bounds__(256) prep_WT(const float* __restrict__ Wk,
                                               const float* __restrict__ Wr,
                                               f16* __restrict__ WT) {
  const int blk = blockIdx.x;  // ni*17 + c
  const int ni = blk / 17, c = blk % 17;
  f16* ob = WT + (size_t)blk * CHH;
  for (int it = threadIdx.x; it < 1024; it += 256) {
    const int col = it >> 3, g = it & 7;
    const int nf = col >> 4, j = col & 15;
    const int gcol = (nf & 3) * 1024 + 32 * ni + 16 * (nf >> 2) + j;
    const int k0 = 64 * c + 8 * (g ^ (col & 7));
    f16x8 v;
#pragma unroll
    for (int e = 0; e < 8; e++) {
      const int kr = k0 + e;
      const float val = (kr < 64) ? Wk[(size_t)kr * 4096 + gcol]
                                  : Wr[(size_t)(kr - 64) * 4096 + gcol];
      v[e] = (f16)val;
    }
    *(f16x8*)(ob + col * 64 + g * 8) = v;
  }
}

__global__ void __launch_bounds__(256) prep_WPT(const float* __restrict__ Wk,
                                                const float* __restrict__ Wr,
                                                const float* __restrict__ Wd,
                                                f16* __restrict__ WPT) {
  const int blk = blockIdx.x;  // ni*16 + c
  const int ni = blk / 16, c = blk % 16;
  f16* ob = WPT + (size_t)blk * CHH;
  for (int it = threadIdx.x; it < 1024; it += 256) {
    const int col = it >> 3, g = it & 7;
    const int nf = col >> 4, j = col & 15;
    const int gcol = (nf & 3) * 1024 + 32 * ni + 16 * (nf >> 2) + j;
    const int k0 = 64 * c + 8 * (g ^ (col & 7));
    float accv[8];
#pragma unroll
    for (int e = 0; e < 8; e++) accv[e] = Wr[(size_t)(k0 + e) * 4096 + gcol];
#pragma unroll
    for (int i = 0; i < 64; i++) {
      const float wki = Wk[(size_t)i * 4096 + gcol];
#pragma unroll
      for (int e = 0; e < 8; e++)
        accv[e] += Wd[(size_t)(k0 + e) * 64 + i] * wki;
    }
    f16x8 v;
#pragma unroll
    for (int e = 0; e < 8; e++) v[e] = (f16)accv[e];
    *(f16x8*)(ob + col * 64 + g * 8) = v;
  }
}

__global__ void __launch_bounds__(256) prep_b(const float* __restrict__ b, float* __restrict__ bperm) {
  const int x = blockIdx.x * 256 + threadIdx.x;  // 4096
  const int ni = x >> 7, rem = x & 127, nf = rem >> 4, j = rem & 15;
  bperm[x] = b[(nf & 3) * 1024 + 32 * ni + 16 * (nf >> 2) + j];
}

__global__ void __launch_bounds__(256) prep_b2(const float* __restrict__ b,
                                               const float* __restrict__ bd,
                                               const float* __restrict__ Wk,
                                               float* __restrict__ bperm2) {
  const int x = blockIdx.x * 256 + threadIdx.x;  // 4096
  const int ni = x >> 7, rem = x & 127, nf = rem >> 4, j = rem & 15;
  const int col = (nf & 3) * 1024 + 32 * ni + 16 * (nf >> 2) + j;
  float acc = b[col];
#pragma unroll
  for (int i = 0; i < 64; i++) acc += bd[i] * Wk[(size_t)i * 4096 + col];
  bperm2[x] = acc;
}

__global__ void __launch_bounds__(256) prep_x0(const float* __restrict__ inp, f16* __restrict__ xbuf) {
  const int mi = blockIdx.x, tid = threadIdx.x;
  const int r = tid >> 1, c0 = (tid & 1) * 32;
  const float* src = inp + (size_t)(128 * mi + r) * 16384 + c0;
  f16* xo = xbuf + (size_t)mi * CHH + (size_t)r * 64 + c0;
#pragma unroll
  for (int q = 0; q < 4; q++) {
    const float4 a = *(const float4*)(src + q * 8);
    const float4 b = *(const float4*)(src + q * 8 + 4);
    f16x8 v;
    v[0] = (f16)a.x; v[1] = (f16)a.y; v[2] = (f16)a.z; v[3] = (f16)a.w;
    v[4] = (f16)b.x; v[5] = (f16)b.y; v[6] = (f16)b.z; v[7] = (f16)b.w;
    *(f16x8*)(xo + 8 * q) = v;
  }
}

// ---------------- host ----------------
extern "C" void kernel_launch(void* const* d_in, const int* in_sizes, int n_in,
                              void* d_out, int out_size, void* d_ws, size_t ws_size,
                              hipStream_t stream) {
  (void)in_sizes; (void)n_in;
  const float* inputs = (const float*)d_in[0];
  const float* Wk = (const float*)d_in[1];
  const float* Wr = (const float*)d_in[2];
  const float* bv = (const float*)d_in[3];
  const float* Wd = (const float*)d_in[4];
  const float* bd = (const float*)d_in[5];
  const int* oidx = (const int*)d_in[6];
  float* out = (float*)d_out;
  const int n_idx = out_size / (1024 * 64);
  if (n_idx < 1 || n_idx > 8) return;

  char* ws = (char*)d_ws;
  const size_t OFF_WT = 0;                  // 32*17*16KB = 8,912,896
  const size_t OFF_WPT = 8912896;           // 32*16*16KB = 8,388,608
  const size_t OFF_BPERM = 17301504;        // 16,384
  const size_t OFF_BPERM2 = 17317888;       // 16,384
  const size_t OFF_HA = 17334272;           // 4,194,304
  const size_t OFF_XB = 21528576;           // 262,144
  const size_t OFF_PP = 21790720;           // 4,194,304
  const size_t OFF_SYNC = 25985024;         // flags 16KB + rank_ctr 512B
  const size_t NEED = 26001920;
  if (ws_size < NEED) return;

  f16* WT = (f16*)(ws + OFF_WT);
  f16* WPT = (f16*)(ws + OFF_WPT);
  float* bperm = (float*)(ws + OFF_BPERM);
  float* bperm2 = (float*)(ws + OFF_BPERM2);
  f16* hbA = (f16*)(ws + OFF_HA);
  f16* xbuf = (f16*)(ws + OFF_XB);
  float* ppart = (float*)(ws + OFF_PP);
  unsigned* sync = (unsigned*)(ws + OFF_SYNC);

  hipMemsetAsync(hbA, 0, 2097152, stream);   // h parity-0 = zeros
  hipMemsetAsync(sync, 0, 16896, stream);
  hipLaunchKernelGGL(prep_WT, dim3(32 * 17), dim3(256), 0, stream, Wk, Wr, WT);
  hipLaunchKernelGGL(prep_WPT, dim3(32 * 16), dim3(256), 0, stream, Wk, Wr, Wd, WPT);
  hipLaunchKernelGGL(prep_b, dim3(16), dim3(256), 0, stream, bv, bperm);
  hipLaunchKernelGGL(prep_b2, dim3(16), dim3(256), 0, stream, bv, bd, Wk, bperm2);
  hipLaunchKernelGGL(prep_x0, dim3(8), dim3(256), 0, stream, inputs, xbuf);

  hipLaunchKernelGGL(lstm_persist, dim3(256), dim3(512), 0, stream,
                     (const f16*)WT, (const f16*)WPT, inputs,
                     hbA, xbuf, ppart,
                     (const float*)bperm, (const float*)bperm2,
                     Wd, bd, oidx, out, n_idx, sync);
}

// Round 10
// 12500.674 us; speedup vs baseline: 12.5562x; 12.5562x over previous
//
#include <hip/hip_runtime.h>
#include <hip/hip_bf16.h>
#include <stdint.h>

// AutoRegressive LSTM (B=1024, T=256, I=64, U=1024, S=64) on MI355X.
// R10 = R8 (8-wave TLP, proven K-loop/staging) + R6 (pin budget that fits L2)
//     + parallel-arrival per-rank flag barrier (no serialized RMW chain,
//       single-wave poll -- fixes R9's 512-thread polling meltdown).
// B weights: 8 chunks reg-pinned (128 VGPR) + 3 LDS-pinned (48KB) + 6/5
// streamed (3-buf, constexpr vmcnt ledger). Streamed/XCD/step ~3.3MB < L2.

typedef _Float16 f16;
typedef _Float16 f16x8 __attribute__((ext_vector_type(8)));
typedef _Float16 f16x4 __attribute__((ext_vector_type(4)));
typedef float f32x4 __attribute__((ext_vector_type(4)));

#define CHH 8192  // halves per [128 cols][64 k] tile (16KB)
#define RPIN 8    // chunks 0..7 in registers
#define LPIN 3    // chunks 8..10 in LDS
#define PINT (RPIN + LPIN)

template <bool WARM> struct Sch {
  static constexpr int NPOS = WARM ? 17 : 16;
  static constexpr int issues(int q) {
    return (q < NPOS) ? (2 + ((q >= PINT) ? 2 : 0)) : 0;
  }
  static constexpr int waitN(int p) { return issues(p + 1) + issues(p + 2); }
};

__device__ __forceinline__ void gl_lds_a(const char* src_lane, const f16* dst_wave) {
  __builtin_amdgcn_global_load_lds(
      (const __attribute__((address_space(1))) unsigned int*)src_lane,
      (__attribute__((address_space(3))) unsigned int*)dst_wave, 16, 0, 1);  // sc0
}
__device__ __forceinline__ void gl_lds_w(const char* src_lane, const f16* dst_wave) {
  __builtin_amdgcn_global_load_lds(
      (const __attribute__((address_space(1))) unsigned int*)src_lane,
      (__attribute__((address_space(3))) unsigned int*)dst_wave, 16, 0, 0);
}

__device__ __forceinline__ float sigf(float x) { return 1.0f / (1.0f + __expf(-x)); }
__device__ __forceinline__ float tanhfast(float x) { return 1.0f - 2.0f / (__expf(2.0f * x) + 1.0f); }

struct Env {
  const char* hA;      // h input, natural [row][1024] fp16 (bytes)
  const char* xb;      // x tile, natural [row][64] fp16 (bytes)
  const char* panel;   // weight panel base (bytes, 16KB swizzled tiles)
  f16 (*Abuf)[CHH];
  f16 (*Bbuf)[CHH];
  f16* WpL;
  int w, lane, rw, cw, ln15, ln4;
  size_t hoff0, hoff1, xoff0, xoff1;
};

template <bool WARM, int P>
__device__ __forceinline__ void issuePos(Env& e) {
  f16* slot = e.Abuf[P % 3];
  if constexpr (WARM && P == 0) {
    gl_lds_a(e.xb + e.xoff0, slot + e.w * 512);
    gl_lds_a(e.xb + e.xoff1, slot + 4096 + e.w * 512);
  } else {
    const char* base = e.hA + (size_t)(WARM ? P - 1 : P) * 128;
    gl_lds_a(base + e.hoff0, slot + e.w * 512);
    gl_lds_a(base + e.hoff1, slot + 4096 + e.w * 512);
  }
  if constexpr (P >= PINT) {
    f16* bs = e.Bbuf[P % 3];
    const char* src = e.panel + (size_t)P * 16384 + (size_t)e.w * 1024 + (size_t)e.lane * 16;
    gl_lds_w(src, bs + e.w * 512);
    gl_lds_w(src + 8192, bs + 4096 + e.w * 512);
  }
}

template <bool WARM, int P>
__device__ __forceinline__ void computePos(Env& e, const f16x8 (&bpin)[RPIN][2][4],
                                           f32x4 (&acc)[2][4]) {
  const f16* Ab = e.Abuf[P % 3];
#pragma unroll
  for (int kc = 0; kc < 2; kc++) {
    const int gx = ((4 * kc + e.ln4) ^ (e.ln15 & 7)) * 8;
    f16x8 af[2], bf[4];
#pragma unroll
    for (int mf = 0; mf < 2; mf++)
      af[mf] = *(const f16x8*)(Ab + (32 * e.rw + 16 * mf + e.ln15) * 64 + gx);
    if constexpr (P < RPIN) {
#pragma unroll
      for (int nf = 0; nf < 4; nf++) bf[nf] = bpin[P][kc][nf];
    } else if constexpr (P < PINT) {
      const f16* Bb = e.WpL + (P - RPIN) * CHH;
#pragma unroll
      for (int nf = 0; nf < 4; nf++)
        bf[nf] = *(const f16x8*)(Bb + (64 * e.cw + 16 * nf + e.ln15) * 64 + gx);
    } else {
      const f16* Bb = e.Bbuf[P % 3];
#pragma unroll
      for (int nf = 0; nf < 4; nf++)
        bf[nf] = *(const f16x8*)(Bb + (64 * e.cw + 16 * nf + e.ln15) * 64 + gx);
    }
    __builtin_amdgcn_s_setprio(1);
#pragma unroll
    for (int mf = 0; mf < 2; mf++)
#pragma unroll
      for (int nf = 0; nf < 4; nf++)
        acc[mf][nf] = __builtin_amdgcn_mfma_f32_16x16x32_f16(af[mf], bf[nf], acc[mf][nf], 0, 0, 0);
    __builtin_amdgcn_s_setprio(0);
  }
}

template <bool WARM>
__device__ __forceinline__ void runStep(Env& e, const f16x8 (&bpin)[RPIN][2][4],
                                        f32x4 (&acc)[2][4]) {
  issuePos<WARM, 0>(e);
  issuePos<WARM, 1>(e);
#define IT_(P)                                                          \
  if constexpr (P < Sch<WARM>::NPOS) {                                  \
    asm volatile("s_waitcnt vmcnt(%0)" ::"n"(Sch<WARM>::waitN(P)));     \
    __builtin_amdgcn_s_barrier();                                       \
    __builtin_amdgcn_sched_barrier(0);                                  \
    if constexpr (P + 2 < Sch<WARM>::NPOS) issuePos<WARM, P + 2>(e);    \
    computePos<WARM, P>(e, bpin, acc);                                  \
  }
  IT_(0) IT_(1) IT_(2) IT_(3) IT_(4) IT_(5) IT_(6) IT_(7) IT_(8)
  IT_(9) IT_(10) IT_(11) IT_(12) IT_(13) IT_(14) IT_(15) IT_(16)
#undef IT_
}

// ---------------- persistent LSTM kernel ----------------
// grid 256 x 512 threads (8 waves, 2/SIMD), 144KB LDS -> 1 WG/CU, 32/XCD.
__global__ void __launch_bounds__(512, 2) lstm_persist(
    const f16* __restrict__ WT, const f16* __restrict__ WPT,
    const float* __restrict__ inputs,
    f16* __restrict__ hbA, f16* __restrict__ xbuf,
    float* __restrict__ ppart,
    const float* __restrict__ bperm, const float* __restrict__ bperm2,
    const float* __restrict__ Wd, const float* __restrict__ bd,
    const int* __restrict__ oidx, float* __restrict__ out,
    int n_idx, unsigned* __restrict__ sync) {
  const int tid = threadIdx.x;

  __shared__ __align__(16) f16 WpL[LPIN * CHH];  // 48KB pinned B (chunks 8..10)
  __shared__ __align__(16) f16 Abuf[3][CHH];     // 48KB
  __shared__ __align__(16) f16 Bbuf[3][CHH];     // 48KB  (total 144KB)

  unsigned xcd;
  asm("s_getreg_b32 %0, hwreg(HW_REG_XCC_ID)" : "=s"(xcd));
  xcd &= 7u;
  unsigned* flags = sync;                 // [xcd*32 + rank], 4B stride
  unsigned* rank_ctr = sync + 1024;       // [xcd*16]
  if (tid == 0) {
    unsigned r = __hip_atomic_fetch_add(&rank_ctr[xcd * 16], 1u, __ATOMIC_RELAXED,
                                        __HIP_MEMORY_SCOPE_AGENT) & 31u;
    *(volatile unsigned short*)WpL = (unsigned short)r;
  }
  __syncthreads();
  const int ni = (int)*(volatile unsigned short*)WpL;
  __syncthreads();
  const int mi = (int)xcd;
  const int fbase = mi * 32;

  const int w = tid >> 6, lane = tid & 63;
  const int rw = w >> 1, cw = w & 1, ln15 = lane & 15, ln4 = lane >> 4;
  const int u_glob = 32 * ni + 16 * cw + ln15;

  // staging lane constants (R8-proven)
  const int l3 = lane >> 3, g8 = lane & 7;
  const int gsw = g8 ^ (l3 & 7);
  const int row_s = w * 8 + l3;

  Env e;
  e.Abuf = Abuf; e.Bbuf = Bbuf; e.WpL = WpL;
  e.w = w; e.lane = lane; e.rw = rw; e.cw = cw; e.ln15 = ln15; e.ln4 = ln4;
  e.hoff0 = (size_t)row_s * 2048 + (size_t)gsw * 16;
  e.hoff1 = (size_t)(row_s + 64) * 2048 + (size_t)gsw * 16;
  e.xoff0 = (size_t)row_s * 128 + (size_t)gsw * 16;
  e.xoff1 = (size_t)(row_s + 64) * 128 + (size_t)gsw * 16;

  // biases + Wd cols
  float biw[4], bi2[4];
#pragma unroll
  for (int nf = 0; nf < 4; nf++) {
    biw[nf] = bperm[ni * 128 + 64 * cw + 16 * nf + ln15];
    bi2[nf] = bperm2[ni * 128 + 64 * cw + 16 * nf + ln15];
  }
  float wdj[8];
#pragma unroll
  for (int j = 0; j < 8; j++) wdj[j] = 0.f;
  for (int j = 0; j < n_idx; j++) wdj[j] = Wd[(size_t)u_glob * 64 + oidx[j]];

  float cst[2][4];
#pragma unroll
  for (int a = 0; a < 2; a++)
#pragma unroll
    for (int q = 0; q < 4; q++) cst[a][q] = 0.f;

  const char* Wsw = (const char*)(WT + (size_t)ni * 17 * CHH);
  const char* Wsd = (const char*)(WPT + (size_t)ni * 16 * CHH);

  // ---- initial pins (warm panel): regs chunks 0..7, LDS chunks 8..10 ----
  f16x8 bpin[RPIN][2][4];
  {
    const f16* p = (const f16*)Wsw;
#pragma unroll
    for (int cp = 0; cp < RPIN; cp++)
#pragma unroll
      for (int kc = 0; kc < 2; kc++) {
        const int gx = ((4 * kc + ln4) ^ (ln15 & 7)) * 8;
#pragma unroll
        for (int nf = 0; nf < 4; nf++)
          bpin[cp][kc][nf] = *(const f16x8*)(p + (size_t)cp * CHH +
                                             (64 * cw + 16 * nf + ln15) * 64 + gx);
      }
#pragma unroll
    for (int i = 0; i < 6; i++)
      gl_lds_w(Wsw + (size_t)RPIN * 16384 + (size_t)(i * 8 + w) * 1024 + (size_t)lane * 16,
               WpL + (i * 8 + w) * 512);
    asm volatile("s_waitcnt vmcnt(0)" ::: "memory");
  }
  __syncthreads();

  for (int t = 0; t < 319; ++t) {
    // ---- per-XCD barrier: parallel arrivals, single-wave poll ----
    if (t > 0) {
      if (w == 0) {
        const unsigned tgt = (unsigned)t;
        int guard = 0;
        for (;;) {
          unsigned v = 0xFFFFFFFFu;
          if (lane < 32)
            v = __hip_atomic_load(&flags[fbase + lane], __ATOMIC_ACQUIRE,
                                  __HIP_MEMORY_SCOPE_AGENT);
          if (__ballot(v < tgt) == 0ull) break;
          __builtin_amdgcn_s_sleep(2);
          if (++guard > (1 << 26)) break;
        }
      }
      __builtin_amdgcn_s_barrier();
    }

    const bool warm = (t < 256);

    // ---- decode entry: swap pins to W' ----
    if (t == 256) {
      const f16* p = (const f16*)Wsd;
#pragma unroll
      for (int cp = 0; cp < RPIN; cp++)
#pragma unroll
        for (int kc = 0; kc < 2; kc++) {
          const int gx = ((4 * kc + ln4) ^ (ln15 & 7)) * 8;
#pragma unroll
          for (int nf = 0; nf < 4; nf++)
            bpin[cp][kc][nf] = *(const f16x8*)(p + (size_t)cp * CHH +
                                               (64 * cw + 16 * nf + ln15) * 64 + gx);
        }
#pragma unroll
      for (int i = 0; i < 6; i++)
        gl_lds_w(Wsd + (size_t)RPIN * 16384 + (size_t)(i * 8 + w) * 1024 + (size_t)lane * 16,
                 WpL + (i * 8 + w) * 512);
      asm volatile("s_waitcnt vmcnt(0)" ::: "memory");
      __syncthreads();
    }

    e.hA = (const char*)(hbA + (size_t)((t & 1) * 8 + mi) * 131072);
    f16* hW = hbA + (size_t)(((t + 1) & 1) * 8 + mi) * 131072;
    e.xb = (const char*)(xbuf + (size_t)((t & 1) * 8 + mi) * CHH);
    e.panel = warm ? Wsw : Wsd;

    // ---- reduce previous decode step's output partials ----
    if (t >= 256) {
      const int s = t - 256;
      const int sb = (t - 1) & 1;
      const int nwork = 4 * n_idx * 8;
      if (tid < nwork) {
        const int qg = tid & 7, rj = tid >> 3;
        const int j = rj % n_idx, r4 = rj / n_idx;
        const int row = 4 * ni + r4;
        float a2 = 0.f;
#pragma unroll
        for (int qq = 0; qq < 4; qq++) {
          const int q = 4 * qg + qq;
#pragma unroll
          for (int c2 = 0; c2 < 2; c2++) {
            const size_t idx = ((((size_t)(sb * 8 + mi) * 32 + q) * 8 + j) * 2 + c2) * 128 + row;
            a2 += __hip_atomic_load(&ppart[idx], __ATOMIC_RELAXED, __HIP_MEMORY_SCOPE_AGENT);
          }
        }
        a2 += __shfl_xor(a2, 1);
        a2 += __shfl_xor(a2, 2);
        a2 += __shfl_xor(a2, 4);
        if (qg == 0) out[((size_t)(128 * mi + row) * 64 + s) * n_idx + j] = a2 + bd[oidx[j]];
      }
      asm volatile("s_waitcnt vmcnt(0)" ::: "memory");  // clean queue for ledger
    }

    f32x4 acc[2][4];
#pragma unroll
    for (int a = 0; a < 2; a++)
#pragma unroll
      for (int q = 0; q < 4; q++) acc[a][q] = (f32x4){0.f, 0.f, 0.f, 0.f};

    if (warm) runStep<true>(e, bpin, acc);
    else      runStep<false>(e, bpin, acc);

    // ---- epilogue: gates -> c (regs), h (natural [row][1024]) ----
    const float b0 = warm ? biw[0] : bi2[0];
    const float b1 = warm ? biw[1] : bi2[1];
    const float b2v = warm ? biw[2] : bi2[2];
    const float b3 = warm ? biw[3] : bi2[3];
    float hv[2][4];
#pragma unroll
    for (int mf = 0; mf < 2; mf++) {
#pragma unroll
      for (int reg = 0; reg < 4; reg++) {
        const int r = 32 * rw + 16 * mf + 4 * ln4 + reg;
        const float zi = acc[mf][0][reg] + b0;
        const float zf = acc[mf][1][reg] + b1;
        const float zg = acc[mf][2][reg] + b2v;
        const float zo = acc[mf][3][reg] + b3;
        const float cn = sigf(zf) * cst[mf][reg] + sigf(zi) * tanhfast(zg);
        const float hn = sigf(zo) * tanhfast(cn);
        cst[mf][reg] = cn;
        hv[mf][reg] = hn;
        hW[(size_t)r * 1024 + u_glob] = (f16)hn;
      }
    }

    // ---- decode output partials (h(t)·Wd cols) ----
    if (t >= 255) {
      const int sbw = t & 1;
      for (int j = 0; j < n_idx; j++) {
        const float wd = wdj[j];
#pragma unroll
        for (int mf = 0; mf < 2; mf++)
#pragma unroll
          for (int reg = 0; reg < 4; reg++) {
            float v = hv[mf][reg] * wd;
            v += __shfl_xor(v, 1);
            v += __shfl_xor(v, 2);
            v += __shfl_xor(v, 4);
            v += __shfl_xor(v, 8);
            if (ln15 == 0) {
              const int r = 32 * rw + 16 * mf + 4 * ln4 + reg;
              const size_t idx = ((((size_t)(sbw * 8 + mi) * 32 + ni) * 8 + j) * 2 + cw) * 128 + r;
              ppart[idx] = v;
            }
          }
      }
    }

    // ---- distributed x-prep for step t+1 (4 rows per rank, wave 7) ----
    if (warm && (t + 1 < 256) && tid >= 448) {
      const int l = tid - 448;
      const int row = 4 * ni + (l >> 4), cg = l & 15;
      const float4 a = *(const float4*)(inputs + (size_t)(128 * mi + row) * 16384 +
                                        (size_t)(t + 1) * 64 + cg * 4);
      f16x4 v;
      v[0] = (f16)a.x; v[1] = (f16)a.y; v[2] = (f16)a.z; v[3] = (f16)a.w;
      *(f16x4*)(xbuf + (size_t)(((t + 1) & 1) * 8 + mi) * CHH + (size_t)row * 64 + cg * 4) = v;
    }

    // ---- drain, publish completion flag (parallel arrivals) ----
    asm volatile("s_waitcnt vmcnt(0)" ::: "memory");
    __builtin_amdgcn_s_barrier();
    if (tid == 0)
      __hip_atomic_store(&flags[fbase + ni], (unsigned)(t + 1),
                         __ATOMIC_RELEASE, __HIP_MEMORY_SCOPE_AGENT);
  }

  // ---- final: wait all ranks at 319, reduce s=63 ----
  if (w == 0) {
    int guard = 0;
    for (;;) {
      unsigned v = 0xFFFFFFFFu;
      if (lane < 32)
        v = __hip_atomic_load(&flags[fbase + lane], __ATOMIC_ACQUIRE,
                              __HIP_MEMORY_SCOPE_AGENT);
      if (__ballot(v < 319u) == 0ull) break;
      __builtin_amdgcn_s_sleep(2);
      if (++guard > (1 << 26)) break;
    }
  }
  __builtin_amdgcn_s_barrier();
  {
    const int nwork = 4 * n_idx * 8;
    if (tid < nwork) {
      const int qg = tid & 7, rj = tid >> 3;
      const int j = rj % n_idx, r4 = rj / n_idx;
      const int row = 4 * ni + r4;
      float a2 = 0.f;
#pragma unroll
      for (int qq = 0; qq < 4; qq++) {
        const int q = 4 * qg + qq;
#pragma unroll
        for (int c2 = 0; c2 < 2; c2++) {
          const size_t idx = ((((size_t)mi * 32 + q) * 8 + j) * 2 + c2) * 128 + row;
          a2 += __hip_atomic_load(&ppart[idx], __ATOMIC_RELAXED, __HIP_MEMORY_SCOPE_AGENT);
        }
      }
      a2 += __shfl_xor(a2, 1);
      a2 += __shfl_xor(a2, 2);
      a2 += __shfl_xor(a2, 4);
      if (qg == 0) out[((size_t)(128 * mi + row) * 64 + 63) * n_idx + j] = a2 + bd[oidx[j]];
    }
  }
}

// ---------------- prep kernels (R8 layouts, proven) ----------------
__global__ void __launch_bounds__(256) prep_WT(const float* __restrict__ Wk,
                                               const float* __restrict__ Wr,
                                               f16* __restrict__ WT) {
  const int blk = blockIdx.x;  // ni*17 + c
  const int ni = blk / 17, c = blk % 17;
  f16* ob = WT + (size_t)blk * CHH;
  for (int it = threadIdx.x; it < 1024; it += 256) {
    const int col = it >> 3, g = it & 7;
    const int nf = col >> 4, j = col & 15;
    const int gcol = (nf & 3) * 1024 + 32 * ni + 16 * (nf >> 2) + j;
    const int k0 = 64 * c + 8 * (g ^ (col & 7));
    f16x8 v;
#pragma unroll
    for (int e = 0; e < 8; e++) {
      const int kr = k0 + e;
      const float val = (kr < 64) ? Wk[(size_t)kr * 4096 + gcol]
                                  : Wr[(size_t)(kr - 64) * 4096 + gcol];
      v[e] = (f16)val;
    }
    *(f16x8*)(ob + col * 64 + g * 8) = v;
  }
}

__global__ void __launch_bounds__(256) prep_WPT(const float* __restrict__ Wk,
                                                const float* __restrict__ Wr,
                                                const float* __restrict__ Wd,
                                                f16* __restrict__ WPT) {
  const int blk = blockIdx.x;  // ni*16 + c
  const int ni = blk / 16, c = blk % 16;
  f16* ob = WPT + (size_t)blk * CHH;
  for (int it = threadIdx.x; it < 1024; it += 256) {
    const int col = it >> 3, g = it & 7;
    const int nf = col >> 4, j = col & 15;
    const int gcol = (nf & 3) * 1024 + 32 * ni + 16 * (nf >> 2) + j;
    const int k0 = 64 * c + 8 * (g ^ (col & 7));
    float accv[8];
#pragma unroll
    for (int e = 0; e < 8; e++) accv[e] = Wr[(size_t)(k0 + e) * 4096 + gcol];
#pragma unroll
    for (int i = 0; i < 64; i++) {
      const float wki = Wk[(size_t)i * 4096 + gcol];
#pragma unroll
      for (int e = 0; e < 8; e++)
        accv[e] += Wd[(size_t)(k0 + e) * 64 + i] * wki;
    }
    f16x8 v;
#pragma unroll
    for (int e = 0; e < 8; e++) v[e] = (f16)accv[e];
    *(f16x8*)(ob + col * 64 + g * 8) = v;
  }
}

__global__ void __launch_bounds__(256) prep_b(const float* __restrict__ b, float* __restrict__ bperm) {
  const int x = blockIdx.x * 256 + threadIdx.x;  // 4096
  const int ni = x >> 7, rem = x & 127, nf = rem >> 4, j = rem & 15;
  bperm[x] = b[(nf & 3) * 1024 + 32 * ni + 16 * (nf >> 2) + j];
}

__global__ void __launch_bounds__(256) prep_b2(const float* __restrict__ b,
                                               const float* __restrict__ bd,
                                               const float* __restrict__ Wk,
                                               float* __restrict__ bperm2) {
  const int x = blockIdx.x * 256 + threadIdx.x;  // 4096
  const int ni = x >> 7, rem = x & 127, nf = rem >> 4, j = rem & 15;
  const int col = (nf & 3) * 1024 + 32 * ni + 16 * (nf >> 2) + j;
  float acc = b[col];
#pragma unroll
  for (int i = 0; i < 64; i++) acc += bd[i] * Wk[(size_t)i * 4096 + col];
  bperm2[x] = acc;
}

__global__ void __launch_bounds__(256) prep_x0(const float* __restrict__ inp, f16* __restrict__ xbuf) {
  const int mi = blockIdx.x, tid = threadIdx.x;
  const int r = tid >> 1, c0 = (tid & 1) * 32;
  const float* src = inp + (size_t)(128 * mi + r) * 16384 + c0;
  f16* xo = xbuf + (size_t)mi * CHH + (size_t)r * 64 + c0;
#pragma unroll
  for (int q = 0; q < 4; q++) {
    const float4 a = *(const float4*)(src + q * 8);
    const float4 b = *(const float4*)(src + q * 8 + 4);
    f16x8 v;
    v[0] = (f16)a.x; v[1] = (f16)a.y; v[2] = (f16)a.z; v[3] = (f16)a.w;
    v[4] = (f16)b.x; v[5] = (f16)b.y; v[6] = (f16)b.z; v[7] = (f16)b.w;
    *(f16x8*)(xo + 8 * q) = v;
  }
}

// ---------------- host ----------------
extern "C" void kernel_launch(void* const* d_in, const int* in_sizes, int n_in,
                              void* d_out, int out_size, void* d_ws, size_t ws_size,
                              hipStream_t stream) {
  (void)in_sizes; (void)n_in;
  const float* inputs = (const float*)d_in[0];
  const float* Wk = (const float*)d_in[1];
  const float* Wr = (const float*)d_in[2];
  const float* bv = (const float*)d_in[3];
  const float* Wd = (const float*)d_in[4];
  const float* bd = (const float*)d_in[5];
  const int* oidx = (const int*)d_in[6];
  float* out = (float*)d_out;
  const int n_idx = out_size / (1024 * 64);
  if (n_idx < 1 || n_idx > 8) return;

  char* ws = (char*)d_ws;
  const size_t OFF_WT = 0;                  // 32*17*16KB = 8,912,896
  const size_t OFF_WPT = 8912896;           // 32*16*16KB = 8,388,608
  const size_t OFF_BPERM = 17301504;        // 16,384
  const size_t OFF_BPERM2 = 17317888;       // 16,384
  const size_t OFF_HA = 17334272;           // 4,194,304
  const size_t OFF_XB = 21528576;           // 262,144
  const size_t OFF_PP = 21790720;           // 4,194,304
  const size_t OFF_SYNC = 25985024;         // flags 1KB + rank_ctr 512B
  const size_t NEED = 25993216;
  if (ws_size < NEED) return;

  f16* WT = (f16*)(ws + OFF_WT);
  f16* WPT = (f16*)(ws + OFF_WPT);
  float* bperm = (float*)(ws + OFF_BPERM);
  float* bperm2 = (float*)(ws + OFF_BPERM2);
  f16* hbA = (f16*)(ws + OFF_HA);
  f16* xbuf = (f16*)(ws + OFF_XB);
  float* ppart = (float*)(ws + OFF_PP);
  unsigned* sync = (unsigned*)(ws + OFF_SYNC);

  hipMemsetAsync(hbA, 0, 2097152, stream);   // h parity-0 = zeros
  hipMemsetAsync(sync, 0, 8192, stream);
  hipLaunchKernelGGL(prep_WT, dim3(32 * 17), dim3(256), 0, stream, Wk, Wr, WT);
  hipLaunchKernelGGL(prep_WPT, dim3(32 * 16), dim3(256), 0, stream, Wk, Wr, Wd, WPT);
  hipLaunchKernelGGL(prep_b, dim3(16), dim3(256), 0, stream, bv, bperm);
  hipLaunchKernelGGL(prep_b2, dim3(16), dim3(256), 0, stream, bv, bd, Wk, bperm2);
  hipLaunchKernelGGL(prep_x0, dim3(8), dim3(256), 0, stream, inputs, xbuf);

  hipLaunchKernelGGL(lstm_persist, dim3(256), dim3(512), 0, stream,
                     (const f16*)WT, (const f16*)WPT, inputs,
                     hbA, xbuf, ppart,
                     (const float*)bperm, (const float*)bperm2,
                     Wd, bd, oidx, out, n_idx, sync);
}

// Round 11
// 11842.046 us; speedup vs baseline: 13.2546x; 1.0556x over previous
//
#include <hip/hip_runtime.h>
#include <hip/hip_bf16.h>
#include <stdint.h>

// AutoRegressive LSTM (B=1024, T=256, I=64, U=1024, S=64) on MI355X.
// R11: persistent per-XCD kernel, NO K-loop barriers at all.
//  - B weights: 9 chunks pinned in LDS (144KB, can't spill) + 8/7 streamed
//    DIRECT global->register (unswizzled [col][512] layout, compile-time
//    immediate offsets, L1-cached since immutable).
//  - A (h/x): direct global->register, sc0 (L1 bypass), 3-slot FIFO.
//  - Exact constexpr vmcnt ledger; issue c+2 BEFORE the wait (FIFO-correct).
//  - Step sync: relaxed flag store after vmcnt(0) (no agent-release L2
//    writeback); acquire poll by ONE wave, 32 lanes, one load/iter.

typedef _Float16 f16;
typedef _Float16 f16x8 __attribute__((ext_vector_type(8)));
typedef _Float16 f16x4 __attribute__((ext_vector_type(4)));
typedef float f32x4 __attribute__((ext_vector_type(4)));

#define NPIN 9   // B chunks 0..8 pinned in LDS

template <bool WARM> struct S2 {
  static constexpr int NPOS = WARM ? 17 : 16;
  static constexpr int aIss(int p) { return (p < NPOS) ? 4 : 0; }
  static constexpr int bIss(int p) { return (p < NPOS && p >= NPIN) ? 8 : 0; }
  static constexpr int waitN(int p) { return aIss(p + 1) + bIss(p + 1) + aIss(p + 2); }
};

__device__ __forceinline__ void gl_lds_w(const char* src_lane, const f16* dst_wave) {
  __builtin_amdgcn_global_load_lds(
      (const __attribute__((address_space(1))) unsigned int*)src_lane,
      (__attribute__((address_space(3))) unsigned int*)dst_wave, 16, 0, 0);
}

__device__ __forceinline__ float sigf(float x) { return 1.0f / (1.0f + __expf(-x)); }
__device__ __forceinline__ float tanhfast(float x) { return 1.0f - 2.0f / (__expf(2.0f * x) + 1.0f); }

struct Env {
  const char* hAb[2];  // per-mf A base (h rows, natural [row][1024])
  const char* xAb[2];  // per-mf A base into x tile [row][64]
  const char* Bst[4];  // per-nf streamed-B base ([col][512] halves layout)
  const f16* WpB;      // pinned B in LDS
  int lcol[4];         // pinned-B col offsets (halves)
  int gx[2];           // pinned-B swizzled k offsets per kc (halves)
};

template <bool WARM, int C>
__device__ __forceinline__ void issueA(const Env& e, f16x8 (&af)[3][2][2]) {
#pragma unroll
  for (int mf = 0; mf < 2; mf++) {
    if constexpr (WARM && C == 0) {
      asm volatile("global_load_dwordx4 %0, %1, off sc0"
                   : "=v"(af[0][0][mf]) : "v"(e.xAb[mf]));
      asm volatile("global_load_dwordx4 %0, %1, off offset:64 sc0"
                   : "=v"(af[0][1][mf]) : "v"(e.xAb[mf]));
    } else {
      constexpr int off = (WARM ? C - 1 : C) * 128;
      asm volatile("global_load_dwordx4 %0, %1, off offset:%2 sc0"
                   : "=v"(af[C % 3][0][mf]) : "v"(e.hAb[mf]), "n"(off));
      asm volatile("global_load_dwordx4 %0, %1, off offset:%2 sc0"
                   : "=v"(af[C % 3][1][mf]) : "v"(e.hAb[mf]), "n"(off + 64));
    }
  }
}

template <int C>
__device__ __forceinline__ void issueB(const Env& e, f16x8 (&bf)[2][2][4]) {
#pragma unroll
  for (int nf = 0; nf < 4; nf++) {
    asm volatile("global_load_dwordx4 %0, %1, off offset:%2"
                 : "=v"(bf[C & 1][0][nf]) : "v"(e.Bst[nf]), "n"((C - NPIN) * 128));
    asm volatile("global_load_dwordx4 %0, %1, off offset:%2"
                 : "=v"(bf[C & 1][1][nf]) : "v"(e.Bst[nf]), "n"((C - NPIN) * 128 + 64));
  }
}

template <bool WARM, int P>
__device__ __forceinline__ void computePos(const Env& e, const f16x8 (&af)[3][2][2],
                                           const f16x8 (&bf)[2][2][4], f32x4 (&acc)[2][4]) {
#pragma unroll
  for (int kc = 0; kc < 2; kc++) {
    f16x8 b0[4];
    if constexpr (P < NPIN) {
      const f16* Bb = e.WpB + P * 8192;
#pragma unroll
      for (int nf = 0; nf < 4; nf++) b0[nf] = *(const f16x8*)(Bb + e.lcol[nf] + e.gx[kc]);
    } else {
#pragma unroll
      for (int nf = 0; nf < 4; nf++) b0[nf] = bf[P & 1][kc][nf];
    }
    __builtin_amdgcn_s_setprio(1);
#pragma unroll
    for (int mf = 0; mf < 2; mf++)
#pragma unroll
      for (int nf = 0; nf < 4; nf++)
        acc[mf][nf] = __builtin_amdgcn_mfma_f32_16x16x32_f16(af[P % 3][kc][mf], b0[nf],
                                                             acc[mf][nf], 0, 0, 0);
    __builtin_amdgcn_s_setprio(0);
  }
}

template <bool WARM>
__device__ __forceinline__ void runStep(const Env& e, f32x4 (&acc)[2][4]) {
  f16x8 af[3][2][2];
  f16x8 bf[2][2][4];
  issueA<WARM, 0>(e, af);
  issueA<WARM, 1>(e, af);
#define RT_(P)                                                                   \
  if constexpr (P < S2<WARM>::NPOS) {                                            \
    if constexpr (P + 1 >= NPIN && P + 1 < S2<WARM>::NPOS) issueB<P + 1>(e, bf); \
    if constexpr (P + 2 < S2<WARM>::NPOS) issueA<WARM, P + 2>(e, af);            \
    asm volatile("s_waitcnt vmcnt(%0)" ::"n"(S2<WARM>::waitN(P)) : "memory");    \
    __builtin_amdgcn_sched_barrier(0);                                           \
    computePos<WARM, P>(e, af, bf, acc);                                         \
  }
  RT_(0) RT_(1) RT_(2) RT_(3) RT_(4) RT_(5) RT_(6) RT_(7) RT_(8)
  RT_(9) RT_(10) RT_(11) RT_(12) RT_(13) RT_(14) RT_(15) RT_(16)
#undef RT_
}

// ---------------- persistent LSTM kernel ----------------
// grid 256 x 512 threads (8 waves, 2/SIMD), 144KB LDS -> 1 WG/CU, 32/XCD.
// Waves: rw = w>>1 (32-row groups), cw = w&1 (64-col halves).
__global__ void __launch_bounds__(512, 2) lstm_persist(
    const f16* __restrict__ WT, const f16* __restrict__ WPT,
    const f16* __restrict__ WS, const f16* __restrict__ WPS,
    const float* __restrict__ inputs,
    f16* __restrict__ hbA, f16* __restrict__ xbuf,
    float* __restrict__ ppart,
    const float* __restrict__ bperm, const float* __restrict__ bperm2,
    const float* __restrict__ Wd, const float* __restrict__ bd,
    const int* __restrict__ oidx, float* __restrict__ out,
    int n_idx, unsigned* __restrict__ sync) {
  const int tid = threadIdx.x;

  __shared__ __align__(16) f16 WpB[NPIN * 8192];  // 147,456 B pinned B

  unsigned xcd;
  asm("s_getreg_b32 %0, hwreg(HW_REG_XCC_ID)" : "=s"(xcd));
  xcd &= 7u;
  unsigned* flags = sync;                 // [xcd*32 + rank]
  unsigned* rank_ctr = sync + 1024;       // [xcd*16]
  if (tid == 0) {
    unsigned r = __hip_atomic_fetch_add(&rank_ctr[xcd * 16], 1u, __ATOMIC_RELAXED,
                                        __HIP_MEMORY_SCOPE_AGENT) & 31u;
    *(volatile unsigned short*)WpB = (unsigned short)r;
  }
  __syncthreads();
  const int ni = (int)*(volatile unsigned short*)WpB;
  __syncthreads();
  const int mi = (int)xcd;
  const int fbase = mi * 32;

  const int w = tid >> 6, lane = tid & 63;
  const int rw = w >> 1, cw = w & 1, ln15 = lane & 15, ln4 = lane >> 4;
  const int u_glob = 32 * ni + 16 * cw + ln15;

  Env e;
  e.WpB = WpB;
#pragma unroll
  for (int nf = 0; nf < 4; nf++) e.lcol[nf] = (64 * cw + 16 * nf + ln15) * 64;
#pragma unroll
  for (int kc = 0; kc < 2; kc++) e.gx[kc] = ((4 * kc + ln4) ^ (ln15 & 7)) * 8;

  // streamed-B bases (warm); decode swaps at t==256
  const char* BstW[4];
  const char* BstD[4];
#pragma unroll
  for (int nf = 0; nf < 4; nf++) {
    const int col = 64 * cw + 16 * nf + ln15;
    BstW[nf] = (const char*)WS + ((size_t)(ni * 128 + col)) * 1024 + (size_t)ln4 * 16;
    BstD[nf] = (const char*)WPS + ((size_t)(ni * 128 + col)) * 1024 + (size_t)ln4 * 16;
  }

  // biases + Wd cols
  float biw[4], bi2[4];
#pragma unroll
  for (int nf = 0; nf < 4; nf++) {
    biw[nf] = bperm[ni * 128 + 64 * cw + 16 * nf + ln15];
    bi2[nf] = bperm2[ni * 128 + 64 * cw + 16 * nf + ln15];
  }
  float wdj[8];
#pragma unroll
  for (int j = 0; j < 8; j++) wdj[j] = 0.f;
  for (int j = 0; j < n_idx; j++) wdj[j] = Wd[(size_t)u_glob * 64 + oidx[j]];

  float cst[2][4];
#pragma unroll
  for (int a = 0; a < 2; a++)
#pragma unroll
    for (int q = 0; q < 4; q++) cst[a][q] = 0.f;

  // initial LDS pin fill (warm pinned panel: 9 chunks = 18KB/wave = 18 issues)
  {
    const char* p = (const char*)(WT + (size_t)ni * NPIN * 8192);
#pragma unroll
    for (int i = 0; i < 18; i++)
      gl_lds_w(p + (size_t)(i * 8 + w) * 1024 + (size_t)lane * 16, WpB + (i * 8 + w) * 512);
    asm volatile("s_waitcnt vmcnt(0)" ::: "memory");
  }
  __syncthreads();

  const int row0 = 32 * rw + ln15;        // mf=0 row
  const int row1 = 32 * rw + 16 + ln15;   // mf=1 row

  for (int t = 0; t < 319; ++t) {
    // ---- per-XCD flag barrier: single-wave poll, parallel arrivals ----
    if (t > 0) {
      if (w == 0) {
        const unsigned tgt = (unsigned)t;
        int guard = 0;
        for (;;) {
          unsigned v = 0xFFFFFFFFu;
          if (lane < 32)
            v = __hip_atomic_load(&flags[fbase + lane], __ATOMIC_ACQUIRE,
                                  __HIP_MEMORY_SCOPE_AGENT);
          if (__ballot(v < tgt) == 0ull) break;
          __builtin_amdgcn_s_sleep(2);
          if (++guard > (1 << 26)) break;
        }
      }
      __builtin_amdgcn_s_barrier();
    }

    const bool warm = (t < 256);

    // ---- decode entry: refill pinned LDS with W' pinned chunks ----
    if (t == 256) {
      const char* p = (const char*)(WPT + (size_t)ni * NPIN * 8192);
#pragma unroll
      for (int i = 0; i < 18; i++)
        gl_lds_w(p + (size_t)(i * 8 + w) * 1024 + (size_t)lane * 16, WpB + (i * 8 + w) * 512);
      asm volatile("s_waitcnt vmcnt(0)" ::: "memory");
      __syncthreads();
    }

    const char* hA = (const char*)(hbA + (size_t)((t & 1) * 8 + mi) * 131072);
    f16* hW = hbA + (size_t)(((t + 1) & 1) * 8 + mi) * 131072;
    const char* xb = (const char*)(xbuf + (size_t)((t & 1) * 8 + mi) * 8192);
    e.hAb[0] = hA + (size_t)row0 * 2048 + (size_t)ln4 * 16;
    e.hAb[1] = hA + (size_t)row1 * 2048 + (size_t)ln4 * 16;
    e.xAb[0] = xb + (size_t)row0 * 128 + (size_t)ln4 * 16;
    e.xAb[1] = xb + (size_t)row1 * 128 + (size_t)ln4 * 16;
#pragma unroll
    for (int nf = 0; nf < 4; nf++) e.Bst[nf] = warm ? BstW[nf] : BstD[nf];

    // ---- reduce previous decode step's output partials ----
    if (t >= 256) {
      const int s = t - 256;
      const int sb = (t - 1) & 1;
      const int nwork = 4 * n_idx * 8;
      if (tid < nwork) {
        const int qg = tid & 7, rj = tid >> 3;
        const int j = rj % n_idx, r4 = rj / n_idx;
        const int row = 4 * ni + r4;
        float a2 = 0.f;
#pragma unroll
        for (int qq = 0; qq < 4; qq++) {
          const int q = 4 * qg + qq;
#pragma unroll
          for (int c2 = 0; c2 < 2; c2++) {
            const size_t idx = ((((size_t)(sb * 8 + mi) * 32 + q) * 8 + j) * 2 + c2) * 128 + row;
            a2 += __hip_atomic_load(&ppart[idx], __ATOMIC_RELAXED, __HIP_MEMORY_SCOPE_AGENT);
          }
        }
        a2 += __shfl_xor(a2, 1);
        a2 += __shfl_xor(a2, 2);
        a2 += __shfl_xor(a2, 4);
        if (qg == 0) out[((size_t)(128 * mi + row) * 64 + s) * n_idx + j] = a2 + bd[oidx[j]];
      }
      asm volatile("s_waitcnt vmcnt(0)" ::: "memory");  // clean queue for ledger
    }

    f32x4 acc[2][4];
#pragma unroll
    for (int a = 0; a < 2; a++)
#pragma unroll
      for (int q = 0; q < 4; q++) acc[a][q] = (f32x4){0.f, 0.f, 0.f, 0.f};

    if (warm) runStep<true>(e, acc);
    else      runStep<false>(e, acc);

    // ---- epilogue: gates -> c (regs), h (natural [row][1024]) ----
    const float b0 = warm ? biw[0] : bi2[0];
    const float b1 = warm ? biw[1] : bi2[1];
    const float b2v = warm ? biw[2] : bi2[2];
    const float b3 = warm ? biw[3] : bi2[3];
    float hv[2][4];
#pragma unroll
    for (int mf = 0; mf < 2; mf++) {
#pragma unroll
      for (int reg = 0; reg < 4; reg++) {
        const int r = 32 * rw + 16 * mf + 4 * ln4 + reg;
        const float zi = acc[mf][0][reg] + b0;
        const float zf = acc[mf][1][reg] + b1;
        const float zg = acc[mf][2][reg] + b2v;
        const float zo = acc[mf][3][reg] + b3;
        const float cn = sigf(zf) * cst[mf][reg] + sigf(zi) * tanhfast(zg);
        const float hn = sigf(zo) * tanhfast(cn);
        cst[mf][reg] = cn;
        hv[mf][reg] = hn;
        hW[(size_t)r * 1024 + u_glob] = (f16)hn;
      }
    }

    // ---- decode output partials (h(t)·Wd cols) ----
    if (t >= 255) {
      const int sbw = t & 1;
      for (int j = 0; j < n_idx; j++) {
        const float wd = wdj[j];
#pragma unroll
        for (int mf = 0; mf < 2; mf++)
#pragma unroll
          for (int reg = 0; reg < 4; reg++) {
            float v = hv[mf][reg] * wd;
            v += __shfl_xor(v, 1);
            v += __shfl_xor(v, 2);
            v += __shfl_xor(v, 4);
            v += __shfl_xor(v, 8);
            if (ln15 == 0) {
              const int r = 32 * rw + 16 * mf + 4 * ln4 + reg;
              const size_t idx = ((((size_t)(sbw * 8 + mi) * 32 + ni) * 8 + j) * 2 + cw) * 128 + r;
              ppart[idx] = v;
            }
          }
      }
    }

    // ---- distributed x-prep for step t+1 (4 rows per rank, wave 7) ----
    if (warm && (t + 1 < 256) && tid >= 448) {
      const int l = tid - 448;
      const int row = 4 * ni + (l >> 4), cg = l & 15;
      const float4 a = *(const float4*)(inputs + (size_t)(128 * mi + row) * 16384 +
                                        (size_t)(t + 1) * 64 + cg * 4);
      f16x4 v;
      v[0] = (f16)a.x; v[1] = (f16)a.y; v[2] = (f16)a.z; v[3] = (f16)a.w;
      *(f16x4*)(xbuf + (size_t)(((t + 1) & 1) * 8 + mi) * 8192 + (size_t)row * 64 + cg * 4) = v;
    }

    // ---- drain, publish completion flag (relaxed: data already at L2) ----
    asm volatile("s_waitcnt vmcnt(0)" ::: "memory");
    __builtin_amdgcn_s_barrier();
    if (tid == 0)
      __hip_atomic_store(&flags[fbase + ni], (unsigned)(t + 1),
                         __ATOMIC_RELAXED, __HIP_MEMORY_SCOPE_AGENT);
  }

  // ---- final: wait all ranks at 319, reduce s=63 ----
  if (w == 0) {
    int guard = 0;
    for (;;) {
      unsigned v = 0xFFFFFFFFu;
      if (lane < 32)
        v = __hip_atomic_load(&flags[fbase + lane], __ATOMIC_ACQUIRE,
                              __HIP_MEMORY_SCOPE_AGENT);
      if (__ballot(v < 319u) == 0ull) break;
      __builtin_amdgcn_s_sleep(2);
      if (++guard > (1 << 26)) break;
    }
  }
  __builtin_amdgcn_s_barrier();
  {
    const int nwork = 4 * n_idx * 8;
    if (tid < nwork) {
      const int qg = tid & 7, rj = tid >> 3;
      const int j = rj % n_idx, r4 = rj / n_idx;
      const int row = 4 * ni + r4;
      float a2 = 0.f;
#pragma unroll
      for (int qq = 0; qq < 4; qq++) {
        const int q = 4 * qg + qq;
#pragma unroll
        for (int c2 = 0; c2 < 2; c2++) {
          const size_t idx = ((((size_t)mi * 32 + q) * 8 + j) * 2 + c2) * 128 + row;
          a2 += __hip_atomic_load(&ppart[idx], __ATOMIC_RELAXED, __HIP_MEMORY_SCOPE_AGENT);
        }
      }
      a2 += __shfl_xor(a2, 1);
      a2 += __shfl_xor(a2, 2);
      a2 += __shfl_xor(a2, 4);
      if (qg == 0) out[((size_t)(128 * mi + row) * 64 + 63) * n_idx + j] = a2 + bd[oidx[j]];
    }
  }
}

// ---------------- prep kernels ----------------
// gate-col mapping: col n (0..127) of rank ni -> source col
//   nf=n>>4, gate=nf&3, half=nf>>2, u=32ni+16half+(n&15), gcol=gate*1024+u
__device__ __forceinline__ int gcol_of(int ni, int n) {
  const int nf = n >> 4, j = n & 15;
  return (nf & 3) * 1024 + 32 * ni + 16 * (nf >> 2) + j;
}

// pinned warm chunks 0..8, swizzled 16KB tiles (for gl_lds linear fill)
__global__ void __launch_bounds__(256) prep_WT(const float* __restrict__ Wk,
                                               const float* __restrict__ Wr,
                                               f16* __restrict__ WT) {
  const int blk = blockIdx.x;  // ni*9 + c
  const int ni = blk / NPIN, c = blk % NPIN;
  f16* ob = WT + (size_t)blk * 8192;
  for (int it = threadIdx.x; it < 1024; it += 256) {
    const int col = it >> 3, g = it & 7;
    const int gcol = gcol_of(ni, col);
    const int k0 = 64 * c + 8 * (g ^ (col & 7));
    f16x8 v;
#pragma unroll
    for (int e = 0; e < 8; e++) {
      const int kr = k0 + e;
      v[e] = (f16)((kr < 64) ? Wk[(size_t)kr * 4096 + gcol] : Wr[(size_t)(kr - 64) * 4096 + gcol]);
    }
    *(f16x8*)(ob + col * 64 + g * 8) = v;
  }
}

// pinned decode chunks 0..8 of W' = Wd@Wk + Wr, swizzled tiles
__global__ void __launch_bounds__(256) prep_WPT(const float* __restrict__ Wk,
                                                const float* __restrict__ Wr,
                                                const float* __restrict__ Wd,
                                                f16* __restrict__ WPT) {
  const int blk = blockIdx.x;  // ni*9 + c
  const int ni = blk / NPIN, c = blk % NPIN;
  f16* ob = WPT + (size_t)blk * 8192;
  for (int it = threadIdx.x; it < 1024; it += 256) {
    const int col = it >> 3, g = it & 7;
    const int gcol = gcol_of(ni, col);
    const int k0 = 64 * c + 8 * (g ^ (col & 7));
    float accv[8];
#pragma unroll
    for (int e = 0; e < 8; e++) accv[e] = Wr[(size_t)(k0 + e) * 4096 + gcol];
#pragma unroll
    for (int i = 0; i < 64; i++) {
      const float wki = Wk[(size_t)i * 4096 + gcol];
#pragma unroll
      for (int e = 0; e < 8; e++) accv[e] += Wd[(size_t)(k0 + e) * 64 + i] * wki;
    }
    f16x8 v;
#pragma unroll
    for (int e = 0; e < 8; e++) v[e] = (f16)accv[e];
    *(f16x8*)(ob + col * 64 + g * 8) = v;
  }
}

// streamed warm chunks 9..16, plain [ni][col][512] (8 chunks of 64 K)
__global__ void __launch_bounds__(256) prep_WS(const float* __restrict__ Wk,
                                               const float* __restrict__ Wr,
                                               f16* __restrict__ WS) {
  const int blk = blockIdx.x;  // ni*8 + cs
  const int ni = blk / 8, cs = blk % 8;
  const int c = NPIN + cs;
  for (int it = threadIdx.x; it < 1024; it += 256) {
    const int col = it >> 3, g = it & 7;
    const int gcol = gcol_of(ni, col);
    const int k0 = 64 * c + 8 * g;
    f16x8 v;
#pragma unroll
    for (int e = 0; e < 8; e++) {
      const int kr = k0 + e;
      v[e] = (f16)((kr < 64) ? Wk[(size_t)kr * 4096 + gcol] : Wr[(size_t)(kr - 64) * 4096 + gcol]);
    }
    *(f16x8*)(WS + ((size_t)(ni * 128 + col)) * 512 + cs * 64 + g * 8) = v;
  }
}

// streamed decode chunks 9..15 of W', plain [ni][col][512] (7 used)
__global__ void __launch_bounds__(256) prep_WPS(const float* __restrict__ Wk,
                                                const float* __restrict__ Wr,
                                                const float* __restrict__ Wd,
                                                f16* __restrict__ WPS) {
  const int blk = blockIdx.x;  // ni*7 + cs
  const int ni = blk / 7, cs = blk % 7;
  const int c = NPIN + cs;
  for (int it = threadIdx.x; it < 1024; it += 256) {
    const int col = it >> 3, g = it & 7;
    const int gcol = gcol_of(ni, col);
    const int k0 = 64 * c + 8 * g;
    float accv[8];
#pragma unroll
    for (int e = 0; e < 8; e++) accv[e] = Wr[(size_t)(k0 + e) * 4096 + gcol];
#pragma unroll
    for (int i = 0; i < 64; i++) {
      const float wki = Wk[(size_t)i * 4096 + gcol];
#pragma unroll
      for (int e = 0; e < 8; e++) accv[e] += Wd[(size_t)(k0 + e) * 64 + i] * wki;
    }
    f16x8 v;
#pragma unroll
    for (int e = 0; e < 8; e++) v[e] = (f16)accv[e];
    *(f16x8*)(WPS + ((size_t)(ni * 128 + col)) * 512 + cs * 64 + g * 8) = v;
  }
}

__global__ void __launch_bounds__(256) prep_b(const float* __restrict__ b, float* __restrict__ bperm) {
  const int x = blockIdx.x * 256 + threadIdx.x;  // 4096
  const int ni = x >> 7, rem = x & 127;
  bperm[x] = b[gcol_of(ni, rem)];
}

__global__ void __launch_bounds__(256) prep_b2(const float* __restrict__ b,
                                               const float* __restrict__ bd,
                                               const float* __restrict__ Wk,
                                               float* __restrict__ bperm2) {
  const int x = blockIdx.x * 256 + threadIdx.x;  // 4096
  const int ni = x >> 7, rem = x & 127;
  const int col = gcol_of(ni, rem);
  float acc = b[col];
#pragma unroll
  for (int i = 0; i < 64; i++) acc += bd[i] * Wk[(size_t)i * 4096 + col];
  bperm2[x] = acc;
}

__global__ void __launch_bounds__(256) prep_x0(const float* __restrict__ inp, f16* __restrict__ xbuf) {
  const int mi = blockIdx.x, tid = threadIdx.x;
  const int r = tid >> 1, c0 = (tid & 1) * 32;
  const float* src = inp + (size_t)(128 * mi + r) * 16384 + c0;
  f16* xo = xbuf + (size_t)mi * 8192 + (size_t)r * 64 + c0;
#pragma unroll
  for (int q = 0; q < 4; q++) {
    const float4 a = *(const float4*)(src + q * 8);
    const float4 b = *(const float4*)(src + q * 8 + 4);
    f16x8 v;
    v[0] = (f16)a.x; v[1] = (f16)a.y; v[2] = (f16)a.z; v[3] = (f16)a.w;
    v[4] = (f16)b.x; v[5] = (f16)b.y; v[6] = (f16)b.z; v[7] = (f16)b.w;
    *(f16x8*)(xo + 8 * q) = v;
  }
}

// ---------------- host ----------------
extern "C" void kernel_launch(void* const* d_in, const int* in_sizes, int n_in,
                              void* d_out, int out_size, void* d_ws, size_t ws_size,
                              hipStream_t stream) {
  (void)in_sizes; (void)n_in;
  const float* inputs = (const float*)d_in[0];
  const float* Wk = (const float*)d_in[1];
  const float* Wr = (const float*)d_in[2];
  const float* bv = (const float*)d_in[3];
  const float* Wd = (const float*)d_in[4];
  const float* bd = (const float*)d_in[5];
  const int* oidx = (const int*)d_in[6];
  float* out = (float*)d_out;
  const int n_idx = out_size / (1024 * 64);
  if (n_idx < 1 || n_idx > 8) return;

  char* ws = (char*)d_ws;
  const size_t OFF_WT = 0;                  // 32*9*16KB  = 4,718,592
  const size_t OFF_WPT = 4718592;           // 4,718,592
  const size_t OFF_WS = 9437184;            // 32*128*512*2 = 4,194,304
  const size_t OFF_WPS = 13631488;          // 4,194,304
  const size_t OFF_BPERM = 17825792;        // 16,384
  const size_t OFF_BPERM2 = 17842176;       // 16,384
  const size_t OFF_HA = 17858560;           // 4,194,304
  const size_t OFF_XB = 22052864;           // 262,144
  const size_t OFF_PP = 22315008;           // 4,194,304
  const size_t OFF_SYNC = 26509312;         // 8,192
  const size_t NEED = 26517504;
  if (ws_size < NEED) return;

  f16* WT = (f16*)(ws + OFF_WT);
  f16* WPT = (f16*)(ws + OFF_WPT);
  f16* WS = (f16*)(ws + OFF_WS);
  f16* WPS = (f16*)(ws + OFF_WPS);
  float* bperm = (float*)(ws + OFF_BPERM);
  float* bperm2 = (float*)(ws + OFF_BPERM2);
  f16* hbA = (f16*)(ws + OFF_HA);
  f16* xbuf = (f16*)(ws + OFF_XB);
  float* ppart = (float*)(ws + OFF_PP);
  unsigned* sync = (unsigned*)(ws + OFF_SYNC);

  hipMemsetAsync(hbA, 0, 2097152, stream);   // h parity-0 = zeros
  hipMemsetAsync(sync, 0, 8192, stream);
  hipLaunchKernelGGL(prep_WT, dim3(32 * 9), dim3(256), 0, stream, Wk, Wr, WT);
  hipLaunchKernelGGL(prep_WPT, dim3(32 * 9), dim3(256), 0, stream, Wk, Wr, Wd, WPT);
  hipLaunchKernelGGL(prep_WS, dim3(32 * 8), dim3(256), 0, stream, Wk, Wr, WS);
  hipLaunchKernelGGL(prep_WPS, dim3(32 * 7), dim3(256), 0, stream, Wk, Wr, Wd, WPS);
  hipLaunchKernelGGL(prep_b, dim3(16), dim3(256), 0, stream, bv, bperm);
  hipLaunchKernelGGL(prep_b2, dim3(16), dim3(256), 0, stream, bv, bd, Wk, bperm2);
  hipLaunchKernelGGL(prep_x0, dim3(8), dim3(256), 0, stream, inputs, xbuf);

  hipLaunchKernelGGL(lstm_persist, dim3(256), dim3(512), 0, stream,
                     (const f16*)WT, (const f16*)WPT, (const f16*)WS, (const f16*)WPS,
                     inputs, hbA, xbuf, ppart,
                     (const float*)bperm, (const float*)bperm2,
                     Wd, bd, oidx, out, n_idx, sync);
}